// Round 3
// baseline (733.839 us; speedup 1.0000x reference)
//
#include <hip/hip_runtime.h>

#define N_PTS 786432
#define U_VOX 131072

typedef __attribute__((ext_vector_type(8))) short v8s;
typedef __attribute__((ext_vector_type(4))) float v4f;

__device__ __forceinline__ unsigned short f2bf(float x){
    unsigned u = __float_as_uint(x);
    u += 0x7fffu + ((u >> 16) & 1u);          // RNE
    return (unsigned short)(u >> 16);
}
__device__ __forceinline__ float decf(unsigned e){
    unsigned u = (e & 0x80000000u) ? (e & 0x7fffffffu) : ~e;
    return __uint_as_float(u);
}

// ---- fold BN into weights; pack MFMA B-fragment layouts (bf16) --------------
__global__ __launch_bounds__(256) void k_fold(
    const float* __restrict__ bn0, const float* __restrict__ w1,
    const float* __restrict__ b1,  const float* __restrict__ bn2,
    const float* __restrict__ w2,  const float* __restrict__ b2,
    const float* __restrict__ bn5, const float* __restrict__ w3,
    const float* __restrict__ b3,  const float* __restrict__ bn8,
    const float* __restrict__ w4,
    float* __restrict__ w1ff, float* __restrict__ b1ff,
    float* __restrict__ b2f,  float* __restrict__ b3f,
    unsigned short* __restrict__ wp2, unsigned short* __restrict__ wp3,
    unsigned short* __restrict__ wp4)
{
    __shared__ float s0[9],t0[9],s2[64],t2[64],s5[128],t5[128],s8[256],t8[256];
    int tid = threadIdx.x;
    if (tid < 9){  float g=bn0[tid], b=bn0[9+tid],  m=bn0[18+tid],  v=bn0[27+tid];
        float s=g*rsqrtf(v+1e-5f); s0[tid]=s; t0[tid]=b-m*s; }
    if (tid < 64){ float g=bn2[tid], b=bn2[64+tid], m=bn2[128+tid], v=bn2[192+tid];
        float s=g*rsqrtf(v+1e-5f); s2[tid]=s; t2[tid]=b-m*s; }
    if (tid < 128){float g=bn5[tid], b=bn5[128+tid],m=bn5[256+tid], v=bn5[384+tid];
        float s=g*rsqrtf(v+1e-5f); s5[tid]=s; t5[tid]=b-m*s; }
    { float g=bn8[tid], b=bn8[256+tid], m=bn8[512+tid], v=bn8[768+tid];
        float s=g*rsqrtf(v+1e-5f); s8[tid]=s; t8[tid]=b-m*s; }
    __syncthreads();
    if (blockIdx.x == 0){
        for (int i=tid;i<576;i+=256){ int k=i>>6, j=i&63; w1ff[i]=s0[k]*w1[i]*s2[j]; }
        if (tid < 64){ float a=0.f;
            for (int k=0;k<9;k++) a += t0[k]*w1[k*64+tid];
            b1ff[tid]=(a+b1[tid])*s2[tid]+t2[tid]; }
        if (tid<128) b2f[tid]=b2[tid]*s5[tid]+t5[tid];
        b3f[tid]=b3[tid]*s8[tid]+t8[tid];
    }
    const int g0 = blockIdx.x*256 + tid, gstep = 32*256;
    for (int e=g0;e<8192;e+=gstep){          // W2f: 64x128, NT=8
        int i=e&7, l=(e>>3)&63, jt=(e>>9)&7, ks=(e>>12)&1;
        int k=ks*32+((l>>4)<<3)+i, j=jt*16+(l&15);
        wp2[e]=f2bf(w2[k*128+j]*s5[j]);
    }
    for (int e=g0;e<32768;e+=gstep){         // W3f: 128x256, NT=16
        int i=e&7, l=(e>>3)&63, jt=(e>>9)&15, ks=e>>13;
        int k=ks*32+((l>>4)<<3)+i, j=jt*16+(l&15);
        wp3[e]=f2bf(w3[k*256+j]*s8[j]);
    }
    for (int e=g0;e<65536;e+=gstep){         // W4: 256x256, NT=16
        int i=e&7, l=(e>>3)&63, jt=(e>>9)&15, ks=e>>13;
        int k=ks*32+((l>>4)<<3)+i, j=jt*16+(l&15);
        wp4[e]=f2bf(w4[k*256+j]);
    }
}

// ---- counting-sort pipeline: hist -> scan -> scatter ------------------------
__global__ void k_hist(const int* __restrict__ uinv, int* __restrict__ cnt){
    int i=blockIdx.x*256+threadIdx.x;
    atomicAdd(cnt + uinv[i], 1);
}
__global__ void k_scan1(int* __restrict__ cnt, int* __restrict__ bsum){
    __shared__ int s[256];
    int t=threadIdx.x, i=blockIdx.x*256+t;
    int v=cnt[i]; s[t]=v; __syncthreads();
    for (int off=1;off<256;off<<=1){
        int x=(t>=off)?s[t-off]:0; __syncthreads();
        s[t]+=x; __syncthreads();
    }
    cnt[i]=s[t]-v;                       // exclusive within block
    if (t==255) bsum[blockIdx.x]=s[255];
}
__global__ void k_scan2(int* __restrict__ bsum){
    __shared__ int s[512];
    int t=threadIdx.x;
    int v=bsum[t]; s[t]=v; __syncthreads();
    for (int off=1;off<512;off<<=1){
        int x=(t>=off)?s[t-off]:0; __syncthreads();
        s[t]+=x; __syncthreads();
    }
    bsum[t]=s[t]-v;                      // exclusive block bases
}
__global__ void k_scan3(const int* __restrict__ cnt, const int* __restrict__ bsum,
                        int* __restrict__ cur){
    int i=blockIdx.x*256+threadIdx.x;
    cur[i]=cnt[i]+bsum[blockIdx.x];
}
__global__ void k_scatter(const int* __restrict__ uinv, int* __restrict__ cur,
                          int* __restrict__ perm){
    int i=blockIdx.x*256+threadIdx.x;
    int slot=atomicAdd(cur + uinv[i], 1);
    perm[slot]=i;
}

// ---- fused MLP (9->64->128->256->256) + in-block segmented max --------------
template<bool SORTED>
__global__ __launch_bounds__(256) void k_fused(
    const float* __restrict__ cat, const float* __restrict__ occ,
    const int* __restrict__ uinv,  const int* __restrict__ perm,
    const float* __restrict__ w1ff, const float* __restrict__ b1ff,
    const unsigned short* __restrict__ wp2, const float* __restrict__ b2f,
    const unsigned short* __restrict__ wp3, const float* __restrict__ b3f,
    const unsigned short* __restrict__ wp4, const float* __restrict__ b4,
    unsigned* __restrict__ pooled, int* __restrict__ uidx)
{
    __shared__ __align__(16) char smem[40240];
    float* bw   = (float*)smem;                         // 1280 f: w1|b1|b2|b3|b4
    float* socc = (float*)(smem+5120);
    int*   svox = (int*)  (smem+5376);
    int*   spm  = (int*)  (smem+5632);
    int*   vpn  = (int*)  (smem+5888);
    float* scat = (float*)(smem+5904);                  // 64x12 f32
    unsigned short* sh1 = (unsigned short*)(smem+8976); // 64x72 bf16
    unsigned short* sh2 = (unsigned short*)(smem+18192);// 64x136 bf16
    unsigned short* sh3 = (unsigned short*)(smem+5904); // 64x264 bf16 (phased)
    unsigned short* sh4 = (unsigned short*)(smem+5904); // 64x268 u16-enc (phased)

    const int tid = threadIdx.x;
    const int p0  = blockIdx.x*64;

    // stage A: weights + permutation indices
    for (int i=tid;i<576;i+=256) bw[i]=w1ff[i];
    if (tid<64)  bw[576+tid]=b1ff[tid];
    if (tid<128) bw[640+tid]=b2f[tid];
    bw[768+tid]=b3f[tid];
    bw[1024+tid]=b4[tid];
    if (tid<64) spm[tid] = SORTED ? perm[p0+tid] : (p0+tid);
    if (tid==64) vpn[0] = (SORTED && p0>0)        ? uinv[perm[p0-1]]  : -1;
    if (tid==65) vpn[1] = (SORTED && p0+64<N_PTS) ? uinv[perm[p0+64]] : -1;
    __syncthreads();
    // stage B: gathers
    if (tid<64){ int pm=spm[tid]; svox[tid]=uinv[pm]; socc[tid]=occ[pm]; }
    for (int i=tid;i<576;i+=256){ int p=i/9, k=i-p*9;
        scat[p*12+k]=cat[(size_t)spm[p]*9+k]; }
    __syncthreads();

    // ---- layer 1 (VALU): 4 threads/point, 16 cols each ----
    {
        const int p=tid>>2, jq=(tid&3)*16;
        float h[16];
#pragma unroll
        for (int jj=0;jj<16;jj++) h[jj]=bw[576+jq+jj];
#pragma unroll
        for (int k=0;k<9;k++){
            float fv=scat[p*12+k];
#pragma unroll
            for (int jj=0;jj<16;jj++) h[jj] += fv*bw[k*64+jq+jj];
        }
        unsigned pk[8];
#pragma unroll
        for (int q=0;q<8;q++){
            unsigned lo=f2bf(fmaxf(h[2*q],0.f));
            unsigned hi=f2bf(fmaxf(h[2*q+1],0.f));
            pk[q]=lo|(hi<<16);
        }
        uint4* dst=(uint4*)(sh1 + p*72 + jq);
        dst[0]=make_uint4(pk[0],pk[1],pk[2],pk[3]);
        dst[1]=make_uint4(pk[4],pk[5],pk[6],pk[7]);
    }
    __syncthreads();

    const int w=tid>>6, l=tid&63;
    const int lrow=l&15, lkb=(l>>4)<<3;
    v4f acc[4][4];

    // ---- layer 2 (MFMA): [64x64]@[64x128]; wave w owns cols [w*32,w*32+32) ----
#pragma unroll
    for (int mt=0;mt<4;mt++)
#pragma unroll
    for (int jt=0;jt<2;jt++)
#pragma unroll
    for (int r=0;r<4;r++) acc[mt][jt][r]=0.f;
    const unsigned short* wp2w = wp2 + (size_t)w*1024 + (size_t)l*8;
#pragma unroll
    for (int ks=0;ks<2;ks++){
        v8s a[4], b[2];
#pragma unroll
        for (int mt=0;mt<4;mt++)
            a[mt]=*(const v8s*)(sh1 + (mt*16+lrow)*72 + ks*32 + lkb);
#pragma unroll
        for (int jt=0;jt<2;jt++)
            b[jt]=*(const v8s*)(wp2w + ks*4096 + jt*512);
#pragma unroll
        for (int mt=0;mt<4;mt++)
#pragma unroll
        for (int jt=0;jt<2;jt++)
            acc[mt][jt]=__builtin_amdgcn_mfma_f32_16x16x32_bf16(a[mt],b[jt],acc[mt][jt],0,0,0);
    }
#pragma unroll
    for (int mt=0;mt<4;mt++)
#pragma unroll
    for (int jt=0;jt<2;jt++)
#pragma unroll
    for (int r=0;r<4;r++){
        int prow=mt*16+(l>>4)*4+r;
        int j=w*32+jt*16+lrow;
        sh2[prow*136+j]=f2bf(fmaxf(acc[mt][jt][r]+bw[640+j],0.f));
    }
    __syncthreads();

    // ---- layer 3 (MFMA): [64x128]@[128x256]; wave w owns cols [w*64,w*64+64) ----
#pragma unroll
    for (int mt=0;mt<4;mt++)
#pragma unroll
    for (int jt=0;jt<4;jt++)
#pragma unroll
    for (int r=0;r<4;r++) acc[mt][jt][r]=0.f;
    const unsigned short* wp3w = wp3 + (size_t)w*2048 + (size_t)l*8;
#pragma unroll
    for (int ks=0;ks<4;ks++){
        v8s a[4], b[4];
#pragma unroll
        for (int mt=0;mt<4;mt++)
            a[mt]=*(const v8s*)(sh2 + (mt*16+lrow)*136 + ks*32 + lkb);
#pragma unroll
        for (int jt=0;jt<4;jt++)
            b[jt]=*(const v8s*)(wp3w + ks*8192 + jt*512);
#pragma unroll
        for (int mt=0;mt<4;mt++)
#pragma unroll
        for (int jt=0;jt<4;jt++)
            acc[mt][jt]=__builtin_amdgcn_mfma_f32_16x16x32_bf16(a[mt],b[jt],acc[mt][jt],0,0,0);
    }
    __syncthreads();   // sh2 reads done; sh3 overlays
#pragma unroll
    for (int mt=0;mt<4;mt++)
#pragma unroll
    for (int jt=0;jt<4;jt++)
#pragma unroll
    for (int r=0;r<4;r++){
        int prow=mt*16+(l>>4)*4+r;
        int j=w*64+jt*16+lrow;
        sh3[prow*264+j]=f2bf(fmaxf(acc[mt][jt][r]+bw[768+j],0.f));
    }
    __syncthreads();

    // ---- layer 4 (MFMA): [64x256]@[256x256] ----
#pragma unroll
    for (int mt=0;mt<4;mt++)
#pragma unroll
    for (int jt=0;jt<4;jt++)
#pragma unroll
    for (int r=0;r<4;r++) acc[mt][jt][r]=0.f;
    const unsigned short* wp4w = wp4 + (size_t)w*2048 + (size_t)l*8;
#pragma unroll
    for (int ks=0;ks<8;ks++){
        v8s a[4], b[4];
#pragma unroll
        for (int mt=0;mt<4;mt++)
            a[mt]=*(const v8s*)(sh3 + (mt*16+lrow)*264 + ks*32 + lkb);
#pragma unroll
        for (int jt=0;jt<4;jt++)
            b[jt]=*(const v8s*)(wp4w + ks*8192 + jt*512);
#pragma unroll
        for (int mt=0;mt<4;mt++)
#pragma unroll
        for (int jt=0;jt<4;jt++)
            acc[mt][jt]=__builtin_amdgcn_mfma_f32_16x16x32_bf16(a[mt],b[jt],acc[mt][jt],0,0,0);
    }
    __syncthreads();   // sh3 reads done; sh4 overlays

    // epilogue: h4 = (acc+b4)*occ -> monotone-encoded bf16 into sh4 (pitch 268)
#pragma unroll
    for (int mt=0;mt<4;mt++)
#pragma unroll
    for (int jt=0;jt<4;jt++)
#pragma unroll
    for (int r=0;r<4;r++){
        int prow=mt*16+(l>>4)*4+r;
        int j=w*64+jt*16+lrow;
        float v=(acc[mt][jt][r]+bw[1024+j])*socc[prow];
        unsigned short b=f2bf(v);
        unsigned short e=(b&0x8000)?(unsigned short)~b:(unsigned short)(b|0x8000);
        sh4[prow*268+j]=e;
    }
    __syncthreads();

    // ---- segmented max over sorted rows: thread = one channel ----
    {
        const int c=tid;
        const int vprev=vpn[0], vnext=vpn[1];
        unsigned m=0; int idxm=0; int vstart=0;
        for (int r=0;r<64;r++){
            unsigned e=sh4[r*268+c]; if (e>m) m=e;
            if (c==0){ int pm=spm[r]; if (pm>idxm) idxm=pm; }
            int v=svox[r];
            bool end = (r==63) || (svox[r+1]!=v);
            if (end){
                bool bnd = (!SORTED) || (vstart==0 && v==vprev) || (r==63 && v==vnext);
                unsigned e32=((unsigned)m<<16) | ((m&0x8000u)?0u:0xFFFFu);
                unsigned* dst=pooled+(size_t)v*256+c;
                if (bnd) atomicMax(dst,e32); else *dst=e32;
                if (c==0){ if (bnd) atomicMax(uidx+v,idxm); else uidx[v]=idxm; }
                m=0; idxm=0; vstart=r+1;
            }
        }
    }
}

// ---- head: relu(pooled@wc+bc)*pooled_occupy; writes outputs 1 and 2 ---------
__global__ __launch_bounds__(256) void k_head(const unsigned* __restrict__ pooled,
        const float* __restrict__ wc, const float* __restrict__ bc,
        const float* __restrict__ occ, const int* __restrict__ uidx,
        float* __restrict__ outf)
{
    __shared__ float swc[4096];
    int tid=threadIdx.x;
    for (int i=tid;i<4096;i+=256) swc[i]=wc[i];
    __syncthreads();
    int j=tid&15, vg=tid>>4;
    int vox=blockIdx.x*16+vg;
    const unsigned* pe=pooled+(size_t)vox*256;
    float acc=bc[j];
    for (int k0=0;k0<256;k0+=4){
        uint4 e=*(const uint4*)(pe+k0);
        acc += decf(e.x)*swc[(k0+0)*16+j];
        acc += decf(e.y)*swc[(k0+1)*16+j];
        acc += decf(e.z)*swc[(k0+2)*16+j];
        acc += decf(e.w)*swc[(k0+3)*16+j];
    }
    float pocc=occ[uidx[vox]];
    outf[524288 + (size_t)vox*16 + j] = fmaxf(acc,0.f)*pocc;
    if (j==0) outf[2621440 + vox] = pocc;
}

// ---- unq pass-through (runs LAST: overwrites the temp region in d_out) ------
__global__ void k_unq(const int* __restrict__ unq, float* __restrict__ o){
    int i=blockIdx.x*256+threadIdx.x;
    o[i]=(float)unq[i];
}

extern "C" void kernel_launch(void* const* d_in, const int* in_sizes, int n_in,
                              void* d_out, int out_size, void* d_ws, size_t ws_size,
                              hipStream_t stream)
{
    const float* cat =(const float*)d_in[0];
    const float* occ =(const float*)d_in[1];
    const int*   unq =(const int*)  d_in[2];
    const int*   uinv=(const int*)  d_in[3];
    const float* bn0 =(const float*)d_in[4];
    const float* w1  =(const float*)d_in[5];
    const float* b1  =(const float*)d_in[6];
    const float* bn2 =(const float*)d_in[7];
    const float* w2  =(const float*)d_in[8];
    const float* b2  =(const float*)d_in[9];
    const float* bn5 =(const float*)d_in[10];
    const float* w3  =(const float*)d_in[11];
    const float* b3  =(const float*)d_in[12];
    const float* bn8 =(const float*)d_in[13];
    const float* w4  =(const float*)d_in[14];
    const float* b4  =(const float*)d_in[15];
    const float* wc  =(const float*)d_in[16];
    const float* bc  =(const float*)d_in[17];

    // ws: 128 MiB pooled + (if room) 3 MB perm
    unsigned* pooled = (unsigned*)d_ws;
    int* perm = (int*)((char*)d_ws + (size_t)U_VOX*256*4);
    const bool sorted = ws_size >= (size_t)U_VOX*256*4 + (size_t)N_PTS*4;

    // temporaries in d_out's unq region [0, 524288) floats; k_unq runs last
    float* outf = (float*)d_out;
    int*   uidx = (int*)d_out;                                 // 131072 ints
    float* w1ff = outf + 131072;                               // 576
    float* b1ff = w1ff + 576;                                  // 64
    float* b2f  = b1ff + 64;                                   // 128
    float* b3f  = b2f  + 128;                                  // 256 -> 132096
    unsigned short* wp2 = (unsigned short*)(outf + 132096);    // 8192 u16
    unsigned short* wp3 = wp2 + 8192;                          // 32768 u16
    unsigned short* wp4 = wp3 + 32768;                         // 65536 u16 -> f185344
    int* cnt  = (int*)(outf + 185344);                         // 131072
    int* cur  = (int*)(outf + 316416);                         // 131072
    int* bsum = (int*)(outf + 447488);                         // 512 -> ends 448000

    hipMemsetAsync((void*)pooled, 0, (size_t)U_VOX*256*4, stream);  // enc(-inf)=0
    hipMemsetAsync((void*)uidx,   0, (size_t)U_VOX*4, stream);
    k_fold<<<32,256,0,stream>>>(bn0,w1,b1,bn2,w2,b2,bn5,w3,b3,bn8,w4,
                                w1ff,b1ff,b2f,b3f,wp2,wp3,wp4);
    if (sorted){
        hipMemsetAsync((void*)cnt, 0, (size_t)U_VOX*4, stream);
        k_hist   <<<N_PTS/256,256,0,stream>>>(uinv,cnt);
        k_scan1  <<<U_VOX/256,256,0,stream>>>(cnt,bsum);
        k_scan2  <<<1,        512,0,stream>>>(bsum);
        k_scan3  <<<U_VOX/256,256,0,stream>>>(cnt,bsum,cur);
        k_scatter<<<N_PTS/256,256,0,stream>>>(uinv,cur,perm);
        k_fused<true><<<N_PTS/64,256,0,stream>>>(cat,occ,uinv,perm,w1ff,b1ff,
                                                 wp2,b2f,wp3,b3f,wp4,b4,pooled,uidx);
    } else {
        k_fused<false><<<N_PTS/64,256,0,stream>>>(cat,occ,uinv,nullptr,w1ff,b1ff,
                                                  wp2,b2f,wp3,b3f,wp4,b4,pooled,uidx);
    }
    k_head<<<U_VOX/16,  256,0,stream>>>(pooled,wc,bc,occ,uidx,outf);
    k_unq <<<U_VOX*4/256,256,0,stream>>>(unq,outf);
}

// Round 4
// 553.943 us; speedup vs baseline: 1.3248x; 1.3248x over previous
//
#include <hip/hip_runtime.h>

#define N_PTS 786432
#define U_VOX 131072

typedef __attribute__((ext_vector_type(8))) short v8s;
typedef __attribute__((ext_vector_type(4))) float v4f;

__device__ __forceinline__ unsigned short f2bf(float x){
    unsigned u = __float_as_uint(x);
    u += 0x7fffu + ((u >> 16) & 1u);          // RNE
    return (unsigned short)(u >> 16);
}
// 16-bit monotone encode of bf16 bits
__device__ __forceinline__ unsigned short enc16(unsigned short b){
    return (b & 0x8000u) ? (unsigned short)~b : (unsigned short)(b | 0x8000u);
}
__device__ __forceinline__ float dec16(unsigned e){   // e: encoded u16 in low bits
    unsigned b = (e & 0x8000u) ? (e ^ 0x8000u) : ((~e) & 0xFFFFu);
    return __uint_as_float(b << 16);
}

// ---- fold BN into weights; pack MFMA B-fragment layouts (bf16) --------------
__global__ __launch_bounds__(256) void k_fold(
    const float* __restrict__ bn0, const float* __restrict__ w1,
    const float* __restrict__ b1,  const float* __restrict__ bn2,
    const float* __restrict__ w2,  const float* __restrict__ b2,
    const float* __restrict__ bn5, const float* __restrict__ w3,
    const float* __restrict__ b3,  const float* __restrict__ bn8,
    const float* __restrict__ w4,
    float* __restrict__ w1ff, float* __restrict__ b1ff,
    float* __restrict__ b2f,  float* __restrict__ b3f,
    unsigned short* __restrict__ wp2, unsigned short* __restrict__ wp3,
    unsigned short* __restrict__ wp4)
{
    __shared__ float s0[9],t0[9],s2[64],t2[64],s5[128],t5[128],s8[256],t8[256];
    int tid = threadIdx.x;
    if (tid < 9){  float g=bn0[tid], b=bn0[9+tid],  m=bn0[18+tid],  v=bn0[27+tid];
        float s=g*rsqrtf(v+1e-5f); s0[tid]=s; t0[tid]=b-m*s; }
    if (tid < 64){ float g=bn2[tid], b=bn2[64+tid], m=bn2[128+tid], v=bn2[192+tid];
        float s=g*rsqrtf(v+1e-5f); s2[tid]=s; t2[tid]=b-m*s; }
    if (tid < 128){float g=bn5[tid], b=bn5[128+tid],m=bn5[256+tid], v=bn5[384+tid];
        float s=g*rsqrtf(v+1e-5f); s5[tid]=s; t5[tid]=b-m*s; }
    { float g=bn8[tid], b=bn8[256+tid], m=bn8[512+tid], v=bn8[768+tid];
        float s=g*rsqrtf(v+1e-5f); s8[tid]=s; t8[tid]=b-m*s; }
    __syncthreads();
    if (blockIdx.x == 0){
        for (int i=tid;i<576;i+=256){ int k=i>>6, j=i&63; w1ff[i]=s0[k]*w1[i]*s2[j]; }
        if (tid < 64){ float a=0.f;
            for (int k=0;k<9;k++) a += t0[k]*w1[k*64+tid];
            b1ff[tid]=(a+b1[tid])*s2[tid]+t2[tid]; }
        if (tid<128) b2f[tid]=b2[tid]*s5[tid]+t5[tid];
        b3f[tid]=b3[tid]*s8[tid]+t8[tid];
    }
    const int g0 = blockIdx.x*256 + tid, gstep = 32*256;
    for (int e=g0;e<8192;e+=gstep){          // W2f: 64x128, NT=8
        int i=e&7, l=(e>>3)&63, jt=(e>>9)&7, ks=(e>>12)&1;
        int k=ks*32+((l>>4)<<3)+i, j=jt*16+(l&15);
        wp2[e]=f2bf(w2[k*128+j]*s5[j]);
    }
    for (int e=g0;e<32768;e+=gstep){         // W3f: 128x256, NT=16
        int i=e&7, l=(e>>3)&63, jt=(e>>9)&15, ks=e>>13;
        int k=ks*32+((l>>4)<<3)+i, j=jt*16+(l&15);
        wp3[e]=f2bf(w3[k*256+j]*s8[j]);
    }
    for (int e=g0;e<65536;e+=gstep){         // W4: 256x256, NT=16
        int i=e&7, l=(e>>3)&63, jt=(e>>9)&15, ks=e>>13;
        int k=ks*32+((l>>4)<<3)+i, j=jt*16+(l&15);
        wp4[e]=f2bf(w4[k*256+j]);
    }
}

// ---- counting-sort pipeline: hist -> scan -> scatter ------------------------
__global__ void k_hist(const int* __restrict__ uinv, int* __restrict__ cnt){
    int i=blockIdx.x*256+threadIdx.x;
    atomicAdd(cnt + uinv[i], 1);
}
__global__ void k_scan1(int* __restrict__ cnt, int* __restrict__ bsum){
    __shared__ int s[256];
    int t=threadIdx.x, i=blockIdx.x*256+t;
    int v=cnt[i]; s[t]=v; __syncthreads();
    for (int off=1;off<256;off<<=1){
        int x=(t>=off)?s[t-off]:0; __syncthreads();
        s[t]+=x; __syncthreads();
    }
    cnt[i]=s[t]-v;
    if (t==255) bsum[blockIdx.x]=s[255];
}
__global__ void k_scan2(int* __restrict__ bsum){
    __shared__ int s[512];
    int t=threadIdx.x;
    int v=bsum[t]; s[t]=v; __syncthreads();
    for (int off=1;off<512;off<<=1){
        int x=(t>=off)?s[t-off]:0; __syncthreads();
        s[t]+=x; __syncthreads();
    }
    bsum[t]=s[t]-v;
}
__global__ void k_scan3(const int* __restrict__ cnt, const int* __restrict__ bsum,
                        int* __restrict__ cur){
    int i=blockIdx.x*256+threadIdx.x;
    cur[i]=cnt[i]+bsum[blockIdx.x];
}
__global__ void k_scatter(const int* __restrict__ uinv, int* __restrict__ cur,
                          int* __restrict__ perm){
    int i=blockIdx.x*256+threadIdx.x;
    int slot=atomicAdd(cur + uinv[i], 1);
    perm[slot]=i;
}

// ---- gather point data into sorted order (coalesced writes) -----------------
__global__ __launch_bounds__(256) void k_gather(const int* __restrict__ perm,
    const float* __restrict__ cat, const float* __restrict__ occ,
    const int* __restrict__ uinv,
    float* __restrict__ scat10, int* __restrict__ svoxS)
{
    int i=blockIdx.x*256+threadIdx.x;
    int pm=perm[i];
    const float* src=cat+(size_t)pm*9;
    float* dst=scat10+(size_t)i*10;
#pragma unroll
    for (int k=0;k<9;k++) dst[k]=src[k];
    dst[9]=occ[pm];
    svoxS[i]=uinv[pm];
}

// ---- max point-index per voxel (L2-resident atomics) ------------------------
__global__ void k_idx(const int* __restrict__ uinv, int* __restrict__ uidx){
    int i=blockIdx.x*256+threadIdx.x;
    atomicMax(uidx + uinv[i], i);
}

// ---- fused MLP (9->64->128->256->256) + in-block segmented max --------------
__global__ __launch_bounds__(256,3) void k_fused(
    const float* __restrict__ scat10g, const int* __restrict__ svoxS,
    const float* __restrict__ w1ff, const float* __restrict__ b1ff,
    const unsigned short* __restrict__ wp2, const float* __restrict__ b2f,
    const unsigned short* __restrict__ wp3, const float* __restrict__ b3f,
    const unsigned short* __restrict__ wp4, const float* __restrict__ b4,
    unsigned* __restrict__ pooled)
{
    __shared__ __align__(16) char smem[39440];
    float* bw   = (float*)smem;                         // 1280 f: w1|b1|b2|b3|b4
    int*   svox = (int*)  (smem+5120);                  // 64
    float* socc = (float*)(smem+5376);                  // 64
    int*   vpn  = (int*)  (smem+5632);                  // 2 (+pad to 5648)
    float* scat = (float*)(smem+5648);                  // 64x10 f32
    unsigned short* sh1 = (unsigned short*)(smem+8208); // 64x72 bf16
    unsigned short* sh2 = (unsigned short*)(smem+17424);// 64x136 bf16
    unsigned short* sh3 = (unsigned short*)(smem+5648); // 64x264 bf16 (phased overlay)
    unsigned short* sh4 = (unsigned short*)(smem+5648); // same buf, encoded u16

    const int tid = threadIdx.x;
    const int p0  = blockIdx.x*64;

    // ---- stage (single phase, fully coalesced) ----
    for (int i=tid;i<576;i+=256) bw[i]=w1ff[i];
    if (tid<64)  bw[576+tid]=b1ff[tid];
    if (tid<128) bw[640+tid]=b2f[tid];
    bw[768+tid]=b3f[tid];
    bw[1024+tid]=b4[tid];
    for (int i=tid;i<640;i+=256) scat[i]=scat10g[(size_t)p0*10+i];
    if (tid<64){ svox[tid]=svoxS[p0+tid];
                 socc[tid]=scat10g[(size_t)(p0+tid)*10+9]; }
    if (tid==0) vpn[0] = (p0>0)           ? svoxS[p0-1]  : -1;
    if (tid==1) vpn[1] = (p0+64<N_PTS)    ? svoxS[p0+64] : -1;
    __syncthreads();

    // ---- layer 1 (VALU): 4 threads/point, 16 cols each ----
    {
        const int p=tid>>2, jq=(tid&3)*16;
        float h[16];
#pragma unroll
        for (int jj=0;jj<16;jj++) h[jj]=bw[576+jq+jj];
#pragma unroll
        for (int k=0;k<9;k++){
            float fv=scat[p*10+k];
#pragma unroll
            for (int jj=0;jj<16;jj++) h[jj] += fv*bw[k*64+jq+jj];
        }
        unsigned pk[8];
#pragma unroll
        for (int q=0;q<8;q++){
            unsigned lo=f2bf(fmaxf(h[2*q],0.f));
            unsigned hi=f2bf(fmaxf(h[2*q+1],0.f));
            pk[q]=lo|(hi<<16);
        }
        uint4* dst=(uint4*)(sh1 + p*72 + jq);
        dst[0]=make_uint4(pk[0],pk[1],pk[2],pk[3]);
        dst[1]=make_uint4(pk[4],pk[5],pk[6],pk[7]);
    }
    __syncthreads();

    const int w=tid>>6, l=tid&63;
    const int lrow=l&15, lkb=(l>>4)<<3;
    v4f acc[4][4];

    // ---- layer 2 (MFMA): [64x64]@[64x128]; wave w owns cols [w*32,w*32+32) ----
#pragma unroll
    for (int mt=0;mt<4;mt++)
#pragma unroll
    for (int jt=0;jt<2;jt++)
#pragma unroll
    for (int r=0;r<4;r++) acc[mt][jt][r]=0.f;
    const unsigned short* wp2w = wp2 + (size_t)w*1024 + (size_t)l*8;
#pragma unroll
    for (int ks=0;ks<2;ks++){
        v8s a[4], b[2];
#pragma unroll
        for (int mt=0;mt<4;mt++)
            a[mt]=*(const v8s*)(sh1 + (mt*16+lrow)*72 + ks*32 + lkb);
#pragma unroll
        for (int jt=0;jt<2;jt++)
            b[jt]=*(const v8s*)(wp2w + ks*4096 + jt*512);
#pragma unroll
        for (int mt=0;mt<4;mt++)
#pragma unroll
        for (int jt=0;jt<2;jt++)
            acc[mt][jt]=__builtin_amdgcn_mfma_f32_16x16x32_bf16(a[mt],b[jt],acc[mt][jt],0,0,0);
    }
#pragma unroll
    for (int mt=0;mt<4;mt++)
#pragma unroll
    for (int jt=0;jt<2;jt++)
#pragma unroll
    for (int r=0;r<4;r++){
        int prow=mt*16+(l>>4)*4+r;
        int j=w*32+jt*16+lrow;
        sh2[prow*136+j]=f2bf(fmaxf(acc[mt][jt][r]+bw[640+j],0.f));
    }
    __syncthreads();

    // ---- layer 3 (MFMA): [64x128]@[128x256]; wave w owns cols [w*64,w*64+64) ----
#pragma unroll
    for (int mt=0;mt<4;mt++)
#pragma unroll
    for (int jt=0;jt<4;jt++)
#pragma unroll
    for (int r=0;r<4;r++) acc[mt][jt][r]=0.f;
    const unsigned short* wp3w = wp3 + (size_t)w*2048 + (size_t)l*8;
#pragma unroll
    for (int ks=0;ks<4;ks++){
        v8s a[4], b[4];
#pragma unroll
        for (int mt=0;mt<4;mt++)
            a[mt]=*(const v8s*)(sh2 + (mt*16+lrow)*136 + ks*32 + lkb);
#pragma unroll
        for (int jt=0;jt<4;jt++)
            b[jt]=*(const v8s*)(wp3w + ks*8192 + jt*512);
#pragma unroll
        for (int mt=0;mt<4;mt++)
#pragma unroll
        for (int jt=0;jt<4;jt++)
            acc[mt][jt]=__builtin_amdgcn_mfma_f32_16x16x32_bf16(a[mt],b[jt],acc[mt][jt],0,0,0);
    }
    __syncthreads();   // sh2 reads done; sh3 overlays
#pragma unroll
    for (int mt=0;mt<4;mt++)
#pragma unroll
    for (int jt=0;jt<4;jt++)
#pragma unroll
    for (int r=0;r<4;r++){
        int prow=mt*16+(l>>4)*4+r;
        int j=w*64+jt*16+lrow;
        sh3[prow*264+j]=f2bf(fmaxf(acc[mt][jt][r]+bw[768+j],0.f));
    }
    __syncthreads();

    // ---- layer 4 (MFMA): [64x256]@[256x256] ----
#pragma unroll
    for (int mt=0;mt<4;mt++)
#pragma unroll
    for (int jt=0;jt<4;jt++)
#pragma unroll
    for (int r=0;r<4;r++) acc[mt][jt][r]=0.f;
    const unsigned short* wp4w = wp4 + (size_t)w*2048 + (size_t)l*8;
#pragma unroll
    for (int ks=0;ks<8;ks++){
        v8s a[4], b[4];
#pragma unroll
        for (int mt=0;mt<4;mt++)
            a[mt]=*(const v8s*)(sh3 + (mt*16+lrow)*264 + ks*32 + lkb);
#pragma unroll
        for (int jt=0;jt<4;jt++)
            b[jt]=*(const v8s*)(wp4w + ks*8192 + jt*512);
#pragma unroll
        for (int mt=0;mt<4;mt++)
#pragma unroll
        for (int jt=0;jt<4;jt++)
            acc[mt][jt]=__builtin_amdgcn_mfma_f32_16x16x32_bf16(a[mt],b[jt],acc[mt][jt],0,0,0);
    }
    __syncthreads();   // sh3 reads done; sh4 (same buffer) written next

    // epilogue: h4=(acc+b4)*occ -> encoded bf16 into sh4 (pitch 264)
#pragma unroll
    for (int mt=0;mt<4;mt++)
#pragma unroll
    for (int jt=0;jt<4;jt++)
#pragma unroll
    for (int r=0;r<4;r++){
        int prow=mt*16+(l>>4)*4+r;
        int j=w*64+jt*16+lrow;
        float v=(acc[mt][jt][r]+bw[1024+j])*socc[prow];
        sh4[prow*264+j]=enc16(f2bf(v));
    }
    __syncthreads();

    // ---- segmented max: thread = channel; ballot mask for segment ends ----
    {
        const int c=tid;
        int vl  = svox[l];
        int vl1 = (l==63)? -2 : svox[l+1];
        unsigned long long mask = __ballot((l==63) || (vl!=vl1));
        const int vp0=vpn[0], vp1=vpn[1];
        unsigned m=0; bool first=true;
        for (int r=0;r<64;r++){
            unsigned e=sh4[r*264+c];
            m = (m>e)?m:e;
            if ((mask>>r)&1ull){
                int v=svox[r];
                unsigned other=(unsigned)__shfl_down((int)m,1);
                unsigned pair=(m&0xFFFFu)|(other<<16);
                if (!(c&1)){
                    unsigned* dst=pooled+(size_t)v*128+(c>>1);
                    bool bnd=(first && v==vp0)||(r==63 && v==vp1);
                    if (bnd){
                        unsigned old=*dst;
                        while (true){
                            unsigned lo=old&0xFFFFu, hi=old>>16;
                            unsigned pl=pair&0xFFFFu, ph=pair>>16;
                            unsigned nv=((lo>pl)?lo:pl)|(((hi>ph)?hi:ph)<<16);
                            if (nv==old) break;
                            unsigned got=atomicCAS(dst,old,nv);
                            if (got==old) break;
                            old=got;
                        }
                    } else {
                        *dst=pair;
                    }
                }
                m=0; first=false;
            }
        }
    }
}

// ---- head: relu(pooled@wc+bc)*pooled_occupy; writes outputs 1 and 2 ---------
__global__ __launch_bounds__(256) void k_head(const unsigned* __restrict__ pooled,
        const float* __restrict__ wc, const float* __restrict__ bc,
        const float* __restrict__ occ, const int* __restrict__ uidx,
        float* __restrict__ outf)
{
    __shared__ float swc[4096];
    int tid=threadIdx.x;
    for (int i=tid;i<4096;i+=256) swc[i]=wc[i];
    __syncthreads();
    int j=tid&15, vg=tid>>4;
    int vox=blockIdx.x*16+vg;
    const unsigned* pe=pooled+(size_t)vox*128;
    float acc=bc[j];
    for (int k0=0;k0<128;k0+=4){
        uint4 e=*(const uint4*)(pe+k0);
        acc += dec16(e.x&0xFFFFu)*swc[(2*k0+0)*16+j] + dec16(e.x>>16)*swc[(2*k0+1)*16+j];
        acc += dec16(e.y&0xFFFFu)*swc[(2*k0+2)*16+j] + dec16(e.y>>16)*swc[(2*k0+3)*16+j];
        acc += dec16(e.z&0xFFFFu)*swc[(2*k0+4)*16+j] + dec16(e.z>>16)*swc[(2*k0+5)*16+j];
        acc += dec16(e.w&0xFFFFu)*swc[(2*k0+6)*16+j] + dec16(e.w>>16)*swc[(2*k0+7)*16+j];
    }
    float pocc=occ[uidx[vox]];
    outf[524288 + (size_t)vox*16 + j] = fmaxf(acc,0.f)*pocc;
    if (j==0) outf[2621440 + vox] = pocc;
}

// ---- unq pass-through (runs LAST: overwrites the temp region in d_out) ------
__global__ void k_unq(const int* __restrict__ unq, float* __restrict__ o){
    int i=blockIdx.x*256+threadIdx.x;
    o[i]=(float)unq[i];
}

extern "C" void kernel_launch(void* const* d_in, const int* in_sizes, int n_in,
                              void* d_out, int out_size, void* d_ws, size_t ws_size,
                              hipStream_t stream)
{
    const float* cat =(const float*)d_in[0];
    const float* occ =(const float*)d_in[1];
    const int*   unq =(const int*)  d_in[2];
    const int*   uinv=(const int*)  d_in[3];
    const float* bn0 =(const float*)d_in[4];
    const float* w1  =(const float*)d_in[5];
    const float* b1  =(const float*)d_in[6];
    const float* bn2 =(const float*)d_in[7];
    const float* w2  =(const float*)d_in[8];
    const float* b2  =(const float*)d_in[9];
    const float* bn5 =(const float*)d_in[10];
    const float* w3  =(const float*)d_in[11];
    const float* b3  =(const float*)d_in[12];
    const float* bn8 =(const float*)d_in[13];
    const float* w4  =(const float*)d_in[14];
    const float* b4  =(const float*)d_in[15];
    const float* wc  =(const float*)d_in[16];
    const float* bc  =(const float*)d_in[17];

    // ws layout (~100 MB total, fits proven >=131MB):
    unsigned* pooled = (unsigned*)d_ws;                               // 64 MiB (u16 pairs)
    int*   perm   = (int*)((char*)d_ws + (size_t)U_VOX*128*4);        // 3 MB
    float* scat10 = (float*)(perm + N_PTS);                           // 30 MB
    int*   svoxS  = (int*)(scat10 + (size_t)N_PTS*10);                // 3 MB

    // temporaries in d_out's unq region [0, 524288) floats; k_unq runs last
    float* outf = (float*)d_out;
    int*   uidx = (int*)d_out;                                 // 131072 ints
    float* w1ff = outf + 131072;                               // 576
    float* b1ff = w1ff + 576;                                  // 64
    float* b2f  = b1ff + 64;                                   // 128
    float* b3f  = b2f  + 128;                                  // 256 -> 132096
    unsigned short* wp2 = (unsigned short*)(outf + 132096);    // 8192 u16
    unsigned short* wp3 = wp2 + 8192;                          // 32768 u16
    unsigned short* wp4 = wp3 + 32768;                         // 65536 u16 -> f185344
    int* cnt  = (int*)(outf + 185344);                         // 131072
    int* cur  = (int*)(outf + 316416);                         // 131072
    int* bsum = (int*)(outf + 447488);                         // 512 -> ends 448000

    hipMemsetAsync((void*)pooled, 0, (size_t)U_VOX*128*4, stream);  // enc16(-inf)=0
    hipMemsetAsync((void*)uidx,   0, (size_t)U_VOX*4, stream);
    hipMemsetAsync((void*)cnt,    0, (size_t)U_VOX*4, stream);
    k_fold   <<<32,        256,0,stream>>>(bn0,w1,b1,bn2,w2,b2,bn5,w3,b3,bn8,w4,
                                           w1ff,b1ff,b2f,b3f,wp2,wp3,wp4);
    k_hist   <<<N_PTS/256, 256,0,stream>>>(uinv,cnt);
    k_scan1  <<<U_VOX/256, 256,0,stream>>>(cnt,bsum);
    k_scan2  <<<1,         512,0,stream>>>(bsum);
    k_scan3  <<<U_VOX/256, 256,0,stream>>>(cnt,bsum,cur);
    k_scatter<<<N_PTS/256, 256,0,stream>>>(uinv,cur,perm);
    k_gather <<<N_PTS/256, 256,0,stream>>>(perm,cat,occ,uinv,scat10,svoxS);
    k_idx    <<<N_PTS/256, 256,0,stream>>>(uinv,uidx);
    k_fused  <<<N_PTS/64,  256,0,stream>>>(scat10,svoxS,w1ff,b1ff,wp2,b2f,
                                           wp3,b3f,wp4,b4,pooled);
    k_head   <<<U_VOX/16,  256,0,stream>>>(pooled,wc,bc,occ,uidx,outf);
    k_unq    <<<U_VOX*4/256,256,0,stream>>>(unq,outf);
}

// Round 6
// 331.629 us; speedup vs baseline: 2.2128x; 1.6704x over previous
//
#include <hip/hip_runtime.h>

#define N_PTS 786432
#define U_VOX 131072
#define NBLK  (N_PTS/64)

typedef __attribute__((ext_vector_type(8))) short v8s;
typedef __attribute__((ext_vector_type(4))) float v4f;

__device__ __forceinline__ unsigned short f2bf(float x){
    unsigned u = __float_as_uint(x);
    u += 0x7fffu + ((u >> 16) & 1u);
    return (unsigned short)(u >> 16);
}
__device__ __forceinline__ unsigned cvtpk(float lo, float hi){
    unsigned r;
    asm("v_cvt_pk_bf16_f32 %0, %1, %2" : "=v"(r) : "v"(lo), "v"(hi));
    return r;
}

// ---- fold BN into weights; pack all MFMA fragment layouts -------------------
__global__ __launch_bounds__(256) void k_fold(
    const float* __restrict__ bn0, const float* __restrict__ w1,
    const float* __restrict__ b1,  const float* __restrict__ bn2,
    const float* __restrict__ w2,  const float* __restrict__ b2,
    const float* __restrict__ bn5, const float* __restrict__ w3,
    const float* __restrict__ b3,  const float* __restrict__ bn8,
    const float* __restrict__ w4,  const float* __restrict__ wc,
    float* __restrict__ b1ff, float* __restrict__ b2f, float* __restrict__ b3f,
    unsigned short* __restrict__ wp1, unsigned short* __restrict__ wp2,
    unsigned short* __restrict__ wp3, unsigned short* __restrict__ wp4,
    unsigned short* __restrict__ wcp)
{
    __shared__ float s0[9],t0[9],s2[64],t2[64],s5[128],t5[128],s8[256],t8[256];
    int tid = threadIdx.x;
    if (tid < 9){  float g=bn0[tid], b=bn0[9+tid],  m=bn0[18+tid],  v=bn0[27+tid];
        float s=g*rsqrtf(v+1e-5f); s0[tid]=s; t0[tid]=b-m*s; }
    if (tid < 64){ float g=bn2[tid], b=bn2[64+tid], m=bn2[128+tid], v=bn2[192+tid];
        float s=g*rsqrtf(v+1e-5f); s2[tid]=s; t2[tid]=b-m*s; }
    if (tid < 128){float g=bn5[tid], b=bn5[128+tid],m=bn5[256+tid], v=bn5[384+tid];
        float s=g*rsqrtf(v+1e-5f); s5[tid]=s; t5[tid]=b-m*s; }
    { float g=bn8[tid], b=bn8[256+tid], m=bn8[512+tid], v=bn8[768+tid];
        float s=g*rsqrtf(v+1e-5f); s8[tid]=s; t8[tid]=b-m*s; }
    __syncthreads();
    if (blockIdx.x == 0){
        if (tid < 64){ float a=0.f;
            for (int k=0;k<9;k++) a += t0[k]*w1[k*64+tid];
            b1ff[tid]=(a+b1[tid])*s2[tid]+t2[tid]; }
        if (tid<128) b2f[tid]=b2[tid]*s5[tid]+t5[tid];
        b3f[tid]=b3[tid]*s8[tid]+t8[tid];
    }
    const int g0 = blockIdx.x*256 + tid, gstep = 32*256;
    for (int e=g0;e<2048;e+=gstep){          // W1f: 32(K,pad)x64, NT=4
        int i=e&7, l=(e>>3)&63, jt=(e>>9)&3;
        int k=((l>>4)<<3)+i, j=jt*16+(l&15);
        wp1[e] = (k<9) ? f2bf(s0[k]*w1[k*64+j]*s2[j]) : (unsigned short)0;
    }
    for (int e=g0;e<8192;e+=gstep){          // W2f: 64x128, NT=8
        int i=e&7, l=(e>>3)&63, jt=(e>>9)&7, ks=(e>>12)&1;
        int k=ks*32+((l>>4)<<3)+i, j=jt*16+(l&15);
        wp2[e]=f2bf(w2[k*128+j]*s5[j]);
    }
    for (int e=g0;e<32768;e+=gstep){         // W3f: 128x256, NT=16
        int i=e&7, l=(e>>3)&63, jt=(e>>9)&15, ks=e>>13;
        int k=ks*32+((l>>4)<<3)+i, j=jt*16+(l&15);
        wp3[e]=f2bf(w3[k*256+j]*s8[j]);
    }
    for (int e=g0;e<65536;e+=gstep){         // W4: 256x256, NT=16
        int i=e&7, l=(e>>3)&63, jt=(e>>9)&15, ks=e>>13;
        int k=ks*32+((l>>4)<<3)+i, j=jt*16+(l&15);
        wp4[e]=f2bf(w4[k*256+j]);
    }
    for (int e=g0;e<4096;e+=gstep){          // Wc: 256x16, NT=1
        int i=e&7, l=(e>>3)&63, ks=e>>9;
        int k=ks*32+((l>>4)<<3)+i, j=l&15;
        wcp[e]=f2bf(wc[k*16+j]);
    }
}

// ---- counting-sort: hist -> scan -> merged scatter/gather/idx ---------------
__global__ void k_hist(const int* __restrict__ uinv, int* __restrict__ cnt){
    int i=blockIdx.x*256+threadIdx.x;
    atomicAdd(cnt + uinv[i], 1);
}
__global__ void k_scan1(int* __restrict__ cnt, int* __restrict__ bsum){
    __shared__ int s[256];
    int t=threadIdx.x, i=blockIdx.x*256+t;
    int v=cnt[i]; s[t]=v; __syncthreads();
    for (int off=1;off<256;off<<=1){
        int x=(t>=off)?s[t-off]:0; __syncthreads();
        s[t]+=x; __syncthreads();
    }
    cnt[i]=s[t]-v;
    if (t==255) bsum[blockIdx.x]=s[255];
}
__global__ void k_scan2(int* __restrict__ bsum){
    __shared__ int s[512];
    int t=threadIdx.x;
    int v=bsum[t]; s[t]=v; __syncthreads();
    for (int off=1;off<512;off<<=1){
        int x=(t>=off)?s[t-off]:0; __syncthreads();
        s[t]+=x; __syncthreads();
    }
    bsum[t]=s[t]-v;
}
__global__ void k_scan3(const int* __restrict__ cnt, const int* __restrict__ bsum,
                        int* __restrict__ cur){
    int i=blockIdx.x*256+threadIdx.x;
    cur[i]=cnt[i]+bsum[blockIdx.x];
}
__global__ void k_scatgath(const int* __restrict__ uinv,
    const float* __restrict__ cat, const float* __restrict__ occ,
    int* __restrict__ cur, int* __restrict__ uidx,
    unsigned short* __restrict__ scat16, int* __restrict__ svoxS)
{
    int i = blockIdx.x*256 + threadIdx.x;
    int v = uinv[i];
    int slot = atomicAdd(cur + v, 1);
    atomicMax(uidx + v, i);
    const float* src = cat + (size_t)i*9;
    unsigned short tmp[16];
#pragma unroll
    for (int k=0;k<9;k++) tmp[k] = f2bf(src[k]);
    tmp[9] = f2bf(occ[i]);
#pragma unroll
    for (int k=10;k<16;k++) tmp[k]=0;
    uint4* dst = (uint4*)(scat16 + (size_t)slot*16);
    dst[0] = *(uint4*)(tmp);
    dst[1] = *(uint4*)(tmp+8);
    svoxS[slot] = v;
}

// ---- fused MLP (MFMA x4, transposed-D) + split segmented max ----------------
__global__ __launch_bounds__(256,4) void k_fused(
    const unsigned short* __restrict__ scat16g, const int* __restrict__ svoxS,
    const unsigned short* __restrict__ wp1, const float* __restrict__ b1ff,
    const unsigned short* __restrict__ wp2, const float* __restrict__ b2f,
    const unsigned short* __restrict__ wp3, const float* __restrict__ b3f,
    const unsigned short* __restrict__ wp4, const float* __restrict__ b4,
    unsigned* __restrict__ pooled, unsigned* __restrict__ bpool)
{
    __shared__ __align__(16) char smem[34320];
    int*   svox = (int*)smem;                  // 64
    float* socc = (float*)(smem+256);          // 64
    int*   vpn  = (int*)(smem+512);            // 2
    float* pmlo = (float*)(smem+528);          // 128
    float* pmhi = (float*)(smem+1040);         // 128
    char*  R1   = smem + 1552;                 // 32 KiB overlay region
    char*  sh1  = R1 + 4096;                   // 64x64ch bf16, pitch 128B
    char*  sh2  = R1 + 12288;                  // 64x128ch bf16, pitch 256B

    const int tid = threadIdx.x;
    const int blk = blockIdx.x;
    const int p0  = blk*64;
    const int w = tid>>6, l = tid&63, lane16 = l&15, hi = l>>4;

    // ---- stage: scat16 (swizzled) + svox + vpn ----
    if (tid < 128){
        uint4 d = *(const uint4*)(scat16g + (size_t)p0*16 + tid*8);
        int p = tid>>1, q = tid&1;
        *(uint4*)(R1 + p*64 + ((q*16) ^ ((p&3)<<4))) = d;
    } else {
        int t2 = tid-128; int p = t2>>1, q = t2&1;
        *(uint4*)(R1 + p*64 + ((32 + q*16) ^ ((p&3)<<4))) = make_uint4(0,0,0,0);
    }
    if (tid < 64) svox[tid] = svoxS[p0 + tid];
    if (tid == 64) vpn[0] = (p0>0) ? svoxS[p0-1] : -1;
    if (tid == 65) vpn[1] = (p0+64<N_PTS) ? svoxS[p0+64] : -1;
    __syncthreads();
    if (tid < 64){
        unsigned short ob = *(unsigned short*)(R1 + tid*64 + (18 ^ ((tid&3)<<4)));
        socc[tid] = __uint_as_float(((unsigned)ob)<<16);
    }

    // ---- L1 (MFMA, K=32 padded): wave w -> channels [16w,16w+16) ----
    {
        v4f bias = *(const v4f*)(b1ff + w*16 + 4*hi);
        v8s aw = *(const v8s*)(wp1 + (size_t)(w*64 + l)*8);
        v4f acc1[4];
#pragma unroll
        for (int mt=0;mt<4;mt++){
            int P = mt*16 + lane16;
            v8s act = *(const v8s*)(R1 + P*64 + ((hi*16) ^ ((P&3)<<4)));
            acc1[mt] = __builtin_amdgcn_mfma_f32_16x16x32_bf16(aw, act, bias, 0,0,0);
        }
#pragma unroll
        for (int mt=0;mt<4;mt++){
            int P = mt*16 + lane16, key = (P&7)<<4;
            int cb = (w*16 + 4*hi)*2;
            float v0=fmaxf(acc1[mt][0],0.f), v1=fmaxf(acc1[mt][1],0.f);
            float v2=fmaxf(acc1[mt][2],0.f), v3=fmaxf(acc1[mt][3],0.f);
            *(unsigned*)(sh1 + P*128 + ((cb  )^key)) = cvtpk(v0,v1);
            *(unsigned*)(sh1 + P*128 + ((cb+4)^key)) = cvtpk(v2,v3);
        }
    }
    __syncthreads();

    // ---- L2 (K=64): wave w -> channels [32w,32w+32) ----
    {
        v4f acc2[4][2];
#pragma unroll
        for (int jj=0;jj<2;jj++){
            v4f bias = *(const v4f*)(b2f + w*32 + jj*16 + 4*hi);
#pragma unroll
            for (int mt=0;mt<4;mt++) acc2[mt][jj]=bias;
        }
#pragma unroll
        for (int ks=0;ks<2;ks++){
            v8s a[4];
#pragma unroll
            for (int mt=0;mt<4;mt++){
                int P = mt*16 + lane16;
                a[mt] = *(const v8s*)(sh1 + P*128 + ((ks*64 + hi*16) ^ ((P&7)<<4)));
            }
#pragma unroll
            for (int jj=0;jj<2;jj++){
                v8s bw = *(const v8s*)(wp2 + (size_t)((ks*8 + w*2 + jj)*64 + l)*8);
#pragma unroll
                for (int mt=0;mt<4;mt++)
                    acc2[mt][jj]=__builtin_amdgcn_mfma_f32_16x16x32_bf16(bw, a[mt], acc2[mt][jj],0,0,0);
            }
        }
#pragma unroll
        for (int mt=0;mt<4;mt++){
            int P = mt*16 + lane16, key = (P&7)<<4;
#pragma unroll
            for (int jj=0;jj<2;jj++){
                int cb = (w*32 + jj*16 + 4*hi)*2;
                float v0=fmaxf(acc2[mt][jj][0],0.f), v1=fmaxf(acc2[mt][jj][1],0.f);
                float v2=fmaxf(acc2[mt][jj][2],0.f), v3=fmaxf(acc2[mt][jj][3],0.f);
                *(unsigned*)(sh2 + P*256 + ((cb  )^key)) = cvtpk(v0,v1);
                *(unsigned*)(sh2 + P*256 + ((cb+4)^key)) = cvtpk(v2,v3);
            }
        }
    }
    __syncthreads();

    // ---- L3 (K=128): wave w -> channels [64w,64w+64) ----
    {
        v4f acc3[4][4];
#pragma unroll
        for (int jj=0;jj<4;jj++){
            v4f bias = *(const v4f*)(b3f + w*64 + jj*16 + 4*hi);
#pragma unroll
            for (int mt=0;mt<4;mt++) acc3[mt][jj]=bias;
        }
#pragma unroll
        for (int ks=0;ks<4;ks++){
            v8s a[4];
#pragma unroll
            for (int mt=0;mt<4;mt++){
                int P = mt*16 + lane16;
                a[mt] = *(const v8s*)(sh2 + P*256 + ((ks*64 + hi*16) ^ ((P&7)<<4)));
            }
#pragma unroll
            for (int jj=0;jj<4;jj++){
                v8s bw = *(const v8s*)(wp3 + (size_t)((ks*16 + w*4 + jj)*64 + l)*8);
#pragma unroll
                for (int mt=0;mt<4;mt++)
                    acc3[mt][jj]=__builtin_amdgcn_mfma_f32_16x16x32_bf16(bw, a[mt], acc3[mt][jj],0,0,0);
            }
        }
        __syncthreads();           // all sh2 reads done; sh3 overlays R1
#pragma unroll
        for (int mt=0;mt<4;mt++){
            int P = mt*16 + lane16, key = (P&7)<<4;
#pragma unroll
            for (int jj=0;jj<4;jj++){
                int cb = (w*64 + jj*16 + 4*hi)*2;
                float v0=fmaxf(acc3[mt][jj][0],0.f), v1=fmaxf(acc3[mt][jj][1],0.f);
                float v2=fmaxf(acc3[mt][jj][2],0.f), v3=fmaxf(acc3[mt][jj][3],0.f);
                *(unsigned*)(R1 + P*512 + ((cb  )^key)) = cvtpk(v0,v1);
                *(unsigned*)(R1 + P*512 + ((cb+4)^key)) = cvtpk(v2,v3);
            }
        }
    }
    __syncthreads();

    // ---- L4 (K=256): wave w -> channels [64w,64w+64); no relu ----
    {
        v4f acc4[4][4];
#pragma unroll
        for (int jj=0;jj<4;jj++){
            v4f bias = *(const v4f*)(b4 + w*64 + jj*16 + 4*hi);
#pragma unroll
            for (int mt=0;mt<4;mt++) acc4[mt][jj]=bias;
        }
#pragma unroll
        for (int ks=0;ks<8;ks++){
            v8s a[4];
#pragma unroll
            for (int mt=0;mt<4;mt++){
                int P = mt*16 + lane16;
                a[mt] = *(const v8s*)(R1 + P*512 + ((ks*64 + hi*16) ^ ((P&7)<<4)));
            }
#pragma unroll
            for (int jj=0;jj<4;jj++){
                v8s bw = *(const v8s*)(wp4 + (size_t)((ks*16 + w*4 + jj)*64 + l)*8);
#pragma unroll
                for (int mt=0;mt<4;mt++)
                    acc4[mt][jj]=__builtin_amdgcn_mfma_f32_16x16x32_bf16(bw, a[mt], acc4[mt][jj],0,0,0);
            }
        }
        __syncthreads();           // all sh3 reads done; sh4 overlays R1
#pragma unroll
        for (int mt=0;mt<4;mt++){
            int P = mt*16 + lane16, key = (P&7)<<4;
            float oc = socc[P];
#pragma unroll
            for (int jj=0;jj<4;jj++){
                int cb = (w*64 + jj*16 + 4*hi)*2;
                *(unsigned*)(R1 + P*512 + ((cb  )^key)) = cvtpk(acc4[mt][jj][0]*oc, acc4[mt][jj][1]*oc);
                *(unsigned*)(R1 + P*512 + ((cb+4)^key)) = cvtpk(acc4[mt][jj][2]*oc, acc4[mt][jj][3]*oc);
            }
        }
    }
    __syncthreads();

    // ---- split segmented max: waves 0-1 rows 0-31, waves 2-3 rows 32-63 ----
    {
        const int half = tid>>7, c = tid&127, rb = half*32;
        int vl = svox[l];
        int vln = (l<63)? svox[l+1] : (int)0x80000000;
        unsigned long long mask = __ballot((l==63) || (vl!=vln));
        const int vp0=vpn[0], vp1=vpn[1];
        const bool cross = (svox[31]==svox[32]);
        float m0=-3.0e38f, m1=-3.0e38f, d0=0.f, d1=0.f;
        int segStart = rb, dEnd = 0; bool defer=false;
#pragma unroll 8
        for (int k=0;k<32;k++){
            int r = rb + k;
            unsigned x = *(const unsigned*)(R1 + r*512 + ((c*4) ^ ((k&7)<<4)));
            m0 = fmaxf(m0, __uint_as_float(x<<16));
            m1 = fmaxf(m1, __uint_as_float(x & 0xFFFF0000u));
            if ((mask>>r)&1ull){
                int v = svox[r];
                if (half==1 && segStart==32 && cross){
                    defer=true; d0=m0; d1=m1; dEnd=r;
                } else {
                    bool bp = (segStart==0) && (v==vp0);
                    bool bn = (r==63) && (v==vp1);
                    unsigned pk = cvtpk(m0,m1);
                    if (bp) bpool[((size_t)blk*2+0)*128 + c] = pk;
                    if (bn) bpool[((size_t)blk*2+1)*128 + c] = pk;
                    if (!bp && !bn) pooled[(size_t)v*128 + c] = pk;
                }
                m0=-3.0e38f; m1=-3.0e38f; segStart=r+1;
            }
        }
        if (half==0 && !((mask>>31)&1ull)){ pmlo[c]=m0; pmhi[c]=m1; }
        __syncthreads();
        if (defer){
            m0 = fmaxf(d0, pmlo[c]); m1 = fmaxf(d1, pmhi[c]);
            unsigned long long lowm = mask & 0x7FFFFFFFull;
            int ts = lowm ? (64 - __clzll(lowm)) : 0;
            int v = svox[32];
            bool bp = (ts==0) && (v==vp0);
            bool bn = (dEnd==63) && (v==vp1);
            unsigned pk = cvtpk(m0,m1);
            if (bp) bpool[((size_t)blk*2+0)*128 + c] = pk;
            if (bn) bpool[((size_t)blk*2+1)*128 + c] = pk;
            if (!bp && !bn) pooled[(size_t)v*128 + c] = pk;
        }
    }
}

// ---- merge cross-block chains from bpool into pooled ------------------------
__global__ __launch_bounds__(256) void k_bmerge(
    const int* __restrict__ cnt, const int* __restrict__ bsum,
    const int* __restrict__ cur, const unsigned* __restrict__ bpool,
    unsigned* __restrict__ pooled)
{
    int tid = threadIdx.x;
    int c = tid & 127, vv = tid>>7;
    int base = blockIdx.x*16 + vv*8;
#pragma unroll
    for (int i=0;i<8;i++){
        int v = base + i;
        int start = cnt[v] + bsum[v>>8];
        int end   = cur[v];
        int bs = start>>6, be = (end-1)>>6;
        if (bs==be) continue;
        unsigned x = bpool[((size_t)bs*2+1)*128 + c];
        float m0 = __uint_as_float(x<<16);
        float m1 = __uint_as_float(x & 0xFFFF0000u);
        for (int b=bs+1;b<be;b++){
            unsigned y = bpool[((size_t)b*2+1)*128 + c];
            m0 = fmaxf(m0, __uint_as_float(y<<16));
            m1 = fmaxf(m1, __uint_as_float(y & 0xFFFF0000u));
        }
        unsigned z = bpool[((size_t)be*2+0)*128 + c];
        m0 = fmaxf(m0, __uint_as_float(z<<16));
        m1 = fmaxf(m1, __uint_as_float(z & 0xFFFF0000u));
        pooled[(size_t)v*128 + c] = cvtpk(m0,m1);
    }
}

// ---- head (MFMA): relu(pooled@wc+bc)*pooled_occupy; outputs 1 and 2 ---------
__global__ __launch_bounds__(256) void k_head(
    const unsigned short* __restrict__ pooled16,
    const unsigned short* __restrict__ wcp, const float* __restrict__ bc,
    const float* __restrict__ occ, const int* __restrict__ uidx,
    float* __restrict__ outf)
{
    __shared__ float pocc[64];
    int tid=threadIdx.x;
    int v0 = blockIdx.x*64;
    if (tid<64){
        float p = occ[uidx[v0+tid]];
        pocc[tid]=p;
        outf[2621440 + v0 + tid] = p;
    }
    __syncthreads();
    int w=tid>>6, l=tid&63, lane16=l&15, hi=l>>4;
    int vb = w*16;
    float bcj = bc[lane16];
    v4f acc = {bcj,bcj,bcj,bcj};
#pragma unroll
    for (int ks=0;ks<8;ks++){
        v8s a = *(const v8s*)(pooled16 + (size_t)(v0 + vb + lane16)*256 + ks*32 + hi*8);
        v8s b = *(const v8s*)(wcp + (size_t)(ks*64 + l)*8);
        acc = __builtin_amdgcn_mfma_f32_16x16x32_bf16(a, b, acc, 0,0,0);
    }
#pragma unroll
    for (int r=0;r<4;r++){
        int vx = vb + 4*hi + r;
        outf[524288 + (size_t)(v0+vx)*16 + lane16] = fmaxf(acc[r],0.f) * pocc[vx];
    }
}

// ---- unq pass-through (runs LAST: overwrites temp region in d_out) ----------
__global__ void k_unq(const int* __restrict__ unq, float* __restrict__ o){
    int i=blockIdx.x*256+threadIdx.x;
    o[i]=(float)unq[i];
}

extern "C" void kernel_launch(void* const* d_in, const int* in_sizes, int n_in,
                              void* d_out, int out_size, void* d_ws, size_t ws_size,
                              hipStream_t stream)
{
    const float* cat =(const float*)d_in[0];
    const float* occ =(const float*)d_in[1];
    const int*   unq =(const int*)  d_in[2];
    const int*   uinv=(const int*)  d_in[3];
    const float* bn0 =(const float*)d_in[4];
    const float* w1  =(const float*)d_in[5];
    const float* b1  =(const float*)d_in[6];
    const float* bn2 =(const float*)d_in[7];
    const float* w2  =(const float*)d_in[8];
    const float* b2  =(const float*)d_in[9];
    const float* bn5 =(const float*)d_in[10];
    const float* w3  =(const float*)d_in[11];
    const float* b3  =(const float*)d_in[12];
    const float* bn8 =(const float*)d_in[13];
    const float* w4  =(const float*)d_in[14];
    const float* b4  =(const float*)d_in[15];
    const float* wc  =(const float*)d_in[16];
    const float* bc  =(const float*)d_in[17];

    // ws: pooled 64MB | scat16 24MB | svoxS 3MB | bpool 12.6MB  (~104MB)
    unsigned* pooled = (unsigned*)d_ws;
    unsigned short* scat16 = (unsigned short*)((char*)d_ws + (size_t)U_VOX*128*4);
    int* svoxS = (int*)(scat16 + (size_t)N_PTS*16);
    unsigned* bpool = (unsigned*)(svoxS + N_PTS);

    // temporaries in d_out's unq region [0, 524288) floats; k_unq runs last
    float* outf = (float*)d_out;
    int*   uidx = (int*)d_out;                                 // 131072 ints
    float* b1ff = outf + 131072;                               // 64
    float* b2f  = b1ff + 64;                                   // 128
    float* b3f  = b2f + 128;                                   // 256 -> 131520
    unsigned short* wp1 = (unsigned short*)(outf + 131520);    // 2048 u16 -> f132544
    unsigned short* wp2 = (unsigned short*)(outf + 132544);    // 8192 u16 -> f136640
    unsigned short* wp3 = (unsigned short*)(outf + 136640);    // 32768 u16 -> f153024
    unsigned short* wp4 = (unsigned short*)(outf + 153024);    // 65536 u16 -> f185792
    unsigned short* wcp = (unsigned short*)(outf + 185792);    // 4096 u16 -> f187840
    int* cnt  = (int*)(outf + 187840);                         // 131072
    int* cur  = (int*)(outf + 318912);                         // 131072
    int* bsum = (int*)(outf + 449984);                         // 512 -> ends 450496

    // uidx MUST be re-zeroed every call: d_out is not re-poisoned between graph
    // replays, and stale unq-floats (~1.1e9 as int) would wedge atomicMax and
    // send k_head's occ[uidx[v]] out of bounds (round-5 crash).
    hipMemsetAsync((void*)uidx, 0, (size_t)U_VOX*4, stream);
    hipMemsetAsync((void*)cnt,  0, (size_t)U_VOX*4, stream);
    k_fold    <<<32,        256,0,stream>>>(bn0,w1,b1,bn2,w2,b2,bn5,w3,b3,bn8,w4,wc,
                                            b1ff,b2f,b3f,wp1,wp2,wp3,wp4,wcp);
    k_hist    <<<N_PTS/256, 256,0,stream>>>(uinv,cnt);
    k_scan1   <<<U_VOX/256, 256,0,stream>>>(cnt,bsum);
    k_scan2   <<<1,         512,0,stream>>>(bsum);
    k_scan3   <<<U_VOX/256, 256,0,stream>>>(cnt,bsum,cur);
    k_scatgath<<<N_PTS/256, 256,0,stream>>>(uinv,cat,occ,cur,uidx,scat16,svoxS);
    k_fused   <<<NBLK,      256,0,stream>>>(scat16,svoxS,wp1,b1ff,wp2,b2f,
                                            wp3,b3f,wp4,b4,pooled,bpool);
    k_bmerge  <<<U_VOX/16,  256,0,stream>>>(cnt,bsum,cur,bpool,pooled);
    k_head    <<<U_VOX/64,  256,0,stream>>>((unsigned short*)pooled,wcp,bc,occ,uidx,outf);
    k_unq     <<<U_VOX*4/256,256,0,stream>>>(unq,outf);
}